// Round 8
// baseline (1597.396 us; speedup 1.0000x reference)
//
#include <hip/hip_runtime.h>

#define N_TOK  65536
#define N_CODE 8192
#define DIM    256

typedef _Float16 f16;
typedef _Float16 f16x8 __attribute__((ext_vector_type(8)));
typedef float    f32x4 __attribute__((ext_vector_type(4)));

// ---------- kernel 1: row sum-of-squares (one wave per row) ----------
// NOTE: summation order (float4 sequential + shfl_down tree) bit-matches the
// reference fp32 reduction — do not change.
__global__ __launch_bounds__(256) void rowsq_kernel(const float* __restrict__ src,
                                                    float* __restrict__ dst, int nrows) {
    int row  = blockIdx.x * 4 + (threadIdx.x >> 6);
    int lane = threadIdx.x & 63;
    if (row >= nrows) return;
    float4 v = ((const float4*)(src + (size_t)row * DIM))[lane];
    float s = v.x * v.x + v.y * v.y + v.z * v.z + v.w * v.w;
#pragma unroll
    for (int off = 32; off; off >>= 1) s += __shfl_down(s, off, 64);
    if (lane == 0) dst[row] = s;
}

// ---------- kernel 2: split W into 2 fp16 limbs, TRANSPOSED (k-major) ----------
// W1t/W2t layout: 16B granule (o, c) at byte o*131072 + c*16 holds
// W?[c][o*8 .. o*8+7]  (o = dim-octet 0..31, c = code 0..8191).
__global__ __launch_bounds__(256) void splitw_t_kernel(const float* __restrict__ W,
                                                       f16* __restrict__ W1t,
                                                       f16* __restrict__ W2t) {
    int g = blockIdx.x * 256 + threadIdx.x;   // octet-task id, < 32*8192
    int o = g >> 13;                          // dim octet 0..31
    int c = g & 8191;                         // code
    const float* p = W + (size_t)c * DIM + o * 8;
    float4 v0 = ((const float4*)p)[0];
    float4 v1 = ((const float4*)p)[1];
    float e[8] = {v0.x, v0.y, v0.z, v0.w, v1.x, v1.y, v1.z, v1.w};
    union { f16 h[8]; uint4 u; } p1, p2;
#pragma unroll
    for (int i = 0; i < 8; ++i) {
        float ws = e[i] * 16384.0f;                  // exact (pow2)
        f16 w1 = (f16)ws;                            // RNE
        float r = (ws - (float)w1) * 2048.0f;        // exact
        p1.h[i] = w1; p2.h[i] = (f16)r;
    }
    size_t byteoff = (size_t)o * 131072 + (size_t)c * 16;
    *(uint4*)((char*)W1t + byteoff) = p1.u;
    *(uint4*)((char*)W2t + byteoff) = p2.u;
}

// ---------- kernel 3: fused MFMA GEMM + argmin, v10 ----------
// v8 structure (639us): 512 blocks x 256 thr, 2 blocks/CU, 32-code tiles,
// k-major conflict-free LDS, 16x16x32. v9 (16-code tiles, 4 domains) showed
// per-tile fixed cost is size-independent -> reverted.
// v8 counters: MfmaUtil 62.8 + VALUBusy 33.4 = 96.2% -> SIMD issue saturated;
// residual = per-wave serial VALU (acc init + 96-op epilogue) phase-locked
// between MFMA bursts.
// v10: accumulator DOUBLE-BUFFER (ping-pong A/B, static names per rule #20).
// Tile t MFMAs -> acc[cur] while tile t-1 epilogue (acc[prev]) interleaves
// into the MFMA issue shadow. setprio brackets REMOVED (side-effecting
// builtin = scheduler fence that would pin the epilogue outside the burst;
// benefit never isolated here, m190 ~0/neg for lockstep GEMM).
// Epilogue order/formula unchanged -> bit-identical output to v8.
__global__ __launch_bounds__(256, 2) void argmin_mfma10(
    const float* __restrict__ X, const f16* __restrict__ W1t, const f16* __restrict__ W2t,
    const float* __restrict__ sxq, const float* __restrict__ esq,
    int* __restrict__ out_idx) {

    __shared__ char wbuf[65536];   // [sel:2][limb:2][o:32][c:32]*16B

    const int tid  = threadIdx.x;
    const int lane = tid & 63;
    const int wv   = tid >> 6;        // 0..3
    const int cl   = lane & 15;       // code-col / token-row within 16
    const int q    = lane >> 4;       // 0..3 k-octet
    const int l5   = lane >> 5;       // 0..1
    const int lane31 = lane & 31;
    const int wavetok0 = blockIdx.x * 128 + wv * 32;

    // ---- A: load 32 tokens x 256 dims, split to 2 f16 limbs, keep in regs ----
    // frag (mt, s): lane holds X[wavetok0 + mt*16 + cl][s*32 + q*8 + j], j=0..7
    f16x8 a1[2][8], a2[2][8];
#pragma unroll
    for (int mt = 0; mt < 2; ++mt)
#pragma unroll
        for (int s = 0; s < 8; ++s) {
            const float* p = X + (size_t)(wavetok0 + mt * 16 + cl) * DIM + s * 32 + q * 8;
            float4 v0 = ((const float4*)p)[0];
            float4 v1 = ((const float4*)p)[1];
            float e[8] = {v0.x, v0.y, v0.z, v0.w, v1.x, v1.y, v1.z, v1.w};
#pragma unroll
            for (int j = 0; j < 8; ++j) {
                f16 h = (f16)e[j];
                float r = (e[j] - (float)h) * 2048.0f;   // exact
                a1[mt][s][j] = h;
                a2[mt][s][j] = (f16)r;
            }
        }

    // sx for this lane's 8 token slots: slot = mt*4+r -> token mt*16 + q*4 + r
    float sxr[8];
#pragma unroll
    for (int mt = 0; mt < 2; ++mt)
#pragma unroll
        for (int r = 0; r < 4; ++r)
            sxr[mt * 4 + r] = sxq[wavetok0 + mt * 16 + q * 4 + r];

    float bestd[8];
    int   besti[8];
#pragma unroll
    for (int i = 0; i < 8; ++i) { bestd[i] = 3.4e38f; besti[i] = 0x7fffffff; }

    // ---- per-lane address constants ----
    const int SLB = l5 * 131072 + lane31 * 16;     // staging source lane part
    const char* RB = wbuf + q * 512 + cl * 16;     // read base (o=s*4+q, c=cl)

    // ---- staging: 32KB per ct (2 limbs x 32 octet-slabs x 512B), 32 wave-
    // instrs, 8/wave. instr fi = wv*8+t: L = fi>>4, octet pair op = fi&15.
    auto stage = [&](int ct2, int sel) {
        const char* g1 = (const char*)W1t + ct2 * 512 + SLB;
        const char* g2 = (const char*)W2t + ct2 * 512 + SLB;
#pragma unroll
        for (int t = 0; t < 8; ++t) {
            int fi = wv * 8 + t;
            int L  = fi >> 4;             // limb (wave-uniform)
            int op = fi & 15;             // octet pair (wave-uniform)
            const char* gsrc = (L ? g2 : g1) + op * 262144;
            char* ldst = wbuf + sel * 32768 + L * 16384 + op * 1024;
            __builtin_amdgcn_global_load_lds(
                (const __attribute__((address_space(1))) unsigned int*)gsrc,
                (__attribute__((address_space(3))) unsigned int*)ldst, 16, 0, 0);
        }
    };

    // accumulator ping-pong sets (named, statically indexed)
    f32x4 Am[2][2], Ac[2][2], Bm[2][2], Bc[2][2];
    float se0A = 0.f, se1A = 0.f, se0B = 0.f, se1B = 0.f;

    // epilogue for tile ctp whose acc is (pm, pc), esq values (s0, s1).
    // d = fl(fl(sx+se) - 2*dot); dot*2^14 = main + 2^-11*cross.
    // candidates ascend in code (nt inner, ct outer): strict < keeps lowest.
    auto epi = [&](f32x4 (&pm)[2][2], f32x4 (&pc)[2][2], float s0, float s1, int ctp) {
#pragma unroll
        for (int mt = 0; mt < 2; ++mt)
#pragma unroll
            for (int nt = 0; nt < 2; ++nt)
#pragma unroll
                for (int r = 0; r < 4; ++r) {
                    float mc = fmaf(pc[mt][nt][r], 4.8828125e-4f, pm[mt][nt][r]);  // *2^-11
                    float t1 = sxr[mt * 4 + r] + (nt ? s1 : s0);
                    float d  = fmaf(-1.220703125e-4f, mc, t1);                     // -2^-13
                    int slot = mt * 4 + r;
                    if (d < bestd[slot]) {
                        bestd[slot] = d;
                        besti[slot] = ctp * 32 + nt * 16 + cl;
                    }
                }
    };

    // one tile: stage ct+1, MFMA ct into (cm, cc), interleave epilogue of
    // ct-1 from (pm, pc), barrier. doEpi=false only for ct=0.
    auto tile_step = [&](int ct, f32x4 (&cm)[2][2], f32x4 (&cc)[2][2],
                         float& c0, float& c1,
                         f32x4 (&pm)[2][2], f32x4 (&pc)[2][2],
                         float p0, float p1, bool doEpi) {
        if (ct + 1 < N_CODE / 32) stage(ct + 1, (ct + 1) & 1);
        c0 = esq[ct * 32 + cl];
        c1 = esq[ct * 32 + 16 + cl];
#pragma unroll
        for (int mt = 0; mt < 2; ++mt)
#pragma unroll
            for (int nt = 0; nt < 2; ++nt) {
                cm[mt][nt] = (f32x4){0.f, 0.f, 0.f, 0.f};
                cc[mt][nt] = (f32x4){0.f, 0.f, 0.f, 0.f};
            }
        const char* va = RB + ((ct & 1) << 15);
#pragma unroll
        for (int s = 0; s < 8; ++s) {
            f16x8 b1[2], b2[2];
            b1[0] = *(const f16x8*)(va + s * 2048);
            b1[1] = *(const f16x8*)(va + s * 2048 + 256);
            b2[0] = *(const f16x8*)(va + s * 2048 + 16384);
            b2[1] = *(const f16x8*)(va + s * 2048 + 16640);
#pragma unroll
            for (int mt = 0; mt < 2; ++mt)
#pragma unroll
                for (int nt = 0; nt < 2; ++nt) {
                    cm[mt][nt] = __builtin_amdgcn_mfma_f32_16x16x32_f16(a1[mt][s], b1[nt], cm[mt][nt], 0, 0, 0);
                    cc[mt][nt] = __builtin_amdgcn_mfma_f32_16x16x32_f16(a2[mt][s], b1[nt], cc[mt][nt], 0, 0, 0);
                    cc[mt][nt] = __builtin_amdgcn_mfma_f32_16x16x32_f16(a1[mt][s], b2[nt], cc[mt][nt], 0, 0, 0);
                }
        }
        if (doEpi) epi(pm, pc, p0, p1, ct - 1);
        __syncthreads();
    };

    stage(0, 0);
    __syncthreads();

    // ct=0 -> A (no epilogue)
    tile_step(0, Am, Ac, se0A, se1A, Bm, Bc, se0B, se1B, false);
    // pairs (odd->B with epi A, even->A with epi B): ct = 1..254
    for (int k = 1; k < 254; k += 2) {
        tile_step(k,     Bm, Bc, se0B, se1B, Am, Ac, se0A, se1A, true);
        tile_step(k + 1, Am, Ac, se0A, se1A, Bm, Bc, se0B, se1B, true);
    }
    // ct=255 -> B with epi(254 from A)
    tile_step(255, Bm, Bc, se0B, se1B, Am, Ac, se0A, se1A, true);
    // final epilogue for ct=255 (acc B)
    epi(Bm, Bc, se0B, se1B, 255);

    // ---- cross-lane reduction over the 16 code-lanes (lex (d, idx) min) ----
#pragma unroll
    for (int slot = 0; slot < 8; ++slot) {
        float d = bestd[slot];
        int   i = besti[slot];
#pragma unroll
        for (int off = 1; off < 16; off <<= 1) {
            float od = __shfl_xor(d, off, 64);
            int   oi = __shfl_xor(i, off, 64);
            if (od < d || (od == d && oi < i)) { d = od; i = oi; }
        }
        if (cl == 0)
            out_idx[wavetok0 + (slot >> 2) * 16 + q * 4 + (slot & 3)] = i;
    }
}

// ---------- kernel 4: gather + straight-through output + loss partials ----------
// atomic spread over 128 accumulators (cut same-address f64 atomic chain
// from 16384 deep to ~128; non-argmin tail 236us -> ~100us).
__global__ __launch_bounds__(256) void finalize_kernel(
    const float* __restrict__ X, const float* __restrict__ W,
    const int* __restrict__ idx, float* __restrict__ outQ,
    float* __restrict__ outI, double* __restrict__ accum) {
    __shared__ double wsum[4];
    int wid  = threadIdx.x >> 6;
    int lane = threadIdx.x & 63;
    int token = blockIdx.x * 4 + wid;
    int id = idx[token];
    float4 x = ((const float4*)(X + (size_t)token * DIM))[lane];
    float4 qv = ((const float4*)(W + (size_t)id * DIM))[lane];
    float4 o;
    o.x = x.x + (qv.x - x.x);
    o.y = x.y + (qv.y - x.y);
    o.z = x.z + (qv.z - x.z);
    o.w = x.w + (qv.w - x.w);
    ((float4*)(outQ + (size_t)token * DIM))[lane] = o;
    float dx = x.x - qv.x, dy = x.y - qv.y, dz = x.z - qv.z, dw = x.w - qv.w;
    float s = dx * dx + dy * dy + dz * dz + dw * dw;
#pragma unroll
    for (int off = 32; off; off >>= 1) s += __shfl_down(s, off, 64);
    if (lane == 0) {
        outI[token] = (float)id;
        wsum[wid] = (double)s;
    }
    __syncthreads();
    if (threadIdx.x == 0) {
        double t = wsum[0] + wsum[1] + wsum[2] + wsum[3];
        atomicAdd(&accum[blockIdx.x & 127], t);
    }
}

// ---------- kernel 5: scalars ----------
__global__ void scalars_kernel(const double* __restrict__ accum, float* __restrict__ out) {
    double mse = 0.0;
    for (int i = 0; i < 128; ++i) mse += accum[i];
    mse /= (double)((size_t)N_TOK * DIM);
    float c = (float)mse;
    out[0] = c + 0.25f * c;
    out[1] = c;
    out[2] = c;
}

extern "C" void kernel_launch(void* const* d_in, const int* in_sizes, int n_in,
                              void* d_out, int out_size, void* d_ws, size_t ws_size,
                              hipStream_t stream) {
    const float* X = (const float*)d_in[0];   // (65536, 256)
    const float* W = (const float*)d_in[1];   // (8192, 256)

    float* outQ = (float*)d_out;
    float* outI = outQ + (size_t)N_TOK * DIM;
    float* outS = outI + N_TOK;

    char* ws = (char*)d_ws;
    double* accum = (double*)ws;                         // @0, 1 KB (128 doubles)
    float* esq = (float*)(ws + 4096);                    // 32 KB
    float* sxq = (float*)(ws + 4096 + 32768);            // 256 KB
    int*   idx = (int*)(ws + 4096 + 32768 + 262144);     // 256 KB
    f16*   W1t = (f16*)(ws + (1 << 20));                 // 4 MB (k-major)
    f16*   W2t = (f16*)(ws + (1 << 20) + 4194304);       // 4 MB (k-major)

    hipMemsetAsync(accum, 0, 128 * sizeof(double), stream);
    splitw_t_kernel<<<N_CODE * 32 / 256, 256, 0, stream>>>(W, W1t, W2t);
    rowsq_kernel<<<N_CODE / 4, 256, 0, stream>>>(W, esq, N_CODE);
    rowsq_kernel<<<N_TOK / 4, 256, 0, stream>>>(X, sxq, N_TOK);
    argmin_mfma10<<<N_TOK / 128, 256, 0, stream>>>(X, W1t, W2t, sxq, esq, idx);
    finalize_kernel<<<N_TOK / 4, 256, 0, stream>>>(X, W, idx, outQ, outI, accum);
    scalars_kernel<<<1, 1, 0, stream>>>(accum, outS);
}

// Round 9
// 767.822 us; speedup vs baseline: 2.0804x; 2.0804x over previous
//
#include <hip/hip_runtime.h>

#define N_TOK  65536
#define N_CODE 8192
#define DIM    256

typedef _Float16 f16;
typedef _Float16 f16x8 __attribute__((ext_vector_type(8)));
typedef float    f32x4 __attribute__((ext_vector_type(4)));

// ---------- kernel 1: row sum-of-squares (one wave per row) ----------
// NOTE: summation order (float4 sequential + shfl_down tree) bit-matches the
// reference fp32 reduction — do not change.
__global__ __launch_bounds__(256) void rowsq_kernel(const float* __restrict__ src,
                                                    float* __restrict__ dst, int nrows) {
    int row  = blockIdx.x * 4 + (threadIdx.x >> 6);
    int lane = threadIdx.x & 63;
    if (row >= nrows) return;
    float4 v = ((const float4*)(src + (size_t)row * DIM))[lane];
    float s = v.x * v.x + v.y * v.y + v.z * v.z + v.w * v.w;
#pragma unroll
    for (int off = 32; off; off >>= 1) s += __shfl_down(s, off, 64);
    if (lane == 0) dst[row] = s;
}

// ---------- kernel 2: split W into 2 fp16 limbs, TRANSPOSED (k-major) ----------
// W1t/W2t layout: 16B granule (o, c) at byte o*131072 + c*16 holds
// W?[c][o*8 .. o*8+7]  (o = dim-octet 0..31, c = code 0..8191).
__global__ __launch_bounds__(256) void splitw_t_kernel(const float* __restrict__ W,
                                                       f16* __restrict__ W1t,
                                                       f16* __restrict__ W2t) {
    int g = blockIdx.x * 256 + threadIdx.x;   // octet-task id, < 32*8192
    int o = g >> 13;                          // dim octet 0..31
    int c = g & 8191;                         // code
    const float* p = W + (size_t)c * DIM + o * 8;
    float4 v0 = ((const float4*)p)[0];
    float4 v1 = ((const float4*)p)[1];
    float e[8] = {v0.x, v0.y, v0.z, v0.w, v1.x, v1.y, v1.z, v1.w};
    union { f16 h[8]; uint4 u; } p1, p2;
#pragma unroll
    for (int i = 0; i < 8; ++i) {
        float ws = e[i] * 16384.0f;                  // exact (pow2)
        f16 w1 = (f16)ws;                            // RNE
        float r = (ws - (float)w1) * 2048.0f;        // exact
        p1.h[i] = w1; p2.h[i] = (f16)r;
    }
    size_t byteoff = (size_t)o * 131072 + (size_t)c * 16;
    *(uint4*)((char*)W1t + byteoff) = p1.u;
    *(uint4*)((char*)W2t + byteoff) = p2.u;
}

// ---------- kernel 3: fused MFMA GEMM + argmin, v11 ----------
// v8 structure (639us best): 512 blocks x 256 thr, 2 blocks/CU, 32-code
// tiles, k-major conflict-free LDS, 16x16x32.
// v10 (lambda ping-pong) put acc arrays in SCRATCH (WRITE_SIZE 1.5GB) —
// lambdas with array-reference params defeat SROA. v11 re-implements the SAME
// schedule as a textual MACRO (code pattern == v8, only array names differ):
//  - acc ping-pong A/B; tile t's s-loop interleaves 2 epilogue slots of tile
//    t-1 after each MFMA group (12 VALU ops issue in the shadow of 12
//    in-flight MFMAs; separate pipes, m114). Slot update order unchanged
//    (nt=0 before nt=1, tiles ascending) -> bit-identical argmin.
//  - zero-init eliminated: s=0 uses a shared zero f32x4 as C-operand
//    (0+x exact in f32; deletes 32 v_mov/tile/wave).
__global__ __launch_bounds__(256, 2) void argmin_mfma11(
    const float* __restrict__ X, const f16* __restrict__ W1t, const f16* __restrict__ W2t,
    const float* __restrict__ sxq, const float* __restrict__ esq,
    int* __restrict__ out_idx) {

    __shared__ char wbuf[65536];   // [sel:2][limb:2][o:32][c:32]*16B

    const int tid  = threadIdx.x;
    const int lane = tid & 63;
    const int wv   = tid >> 6;        // 0..3
    const int cl   = lane & 15;       // code-col / token-row within 16
    const int q    = lane >> 4;       // 0..3 k-octet
    const int l5   = lane >> 5;       // 0..1
    const int lane31 = lane & 31;
    const int wavetok0 = blockIdx.x * 128 + wv * 32;

    // ---- A: load 32 tokens x 256 dims, split to 2 f16 limbs, keep in regs ----
    // frag (mt, s): lane holds X[wavetok0 + mt*16 + cl][s*32 + q*8 + j], j=0..7
    f16x8 a1[2][8], a2[2][8];
#pragma unroll
    for (int mt = 0; mt < 2; ++mt)
#pragma unroll
        for (int s = 0; s < 8; ++s) {
            const float* p = X + (size_t)(wavetok0 + mt * 16 + cl) * DIM + s * 32 + q * 8;
            float4 v0 = ((const float4*)p)[0];
            float4 v1 = ((const float4*)p)[1];
            float e[8] = {v0.x, v0.y, v0.z, v0.w, v1.x, v1.y, v1.z, v1.w};
#pragma unroll
            for (int j = 0; j < 8; ++j) {
                f16 h = (f16)e[j];
                float r = (e[j] - (float)h) * 2048.0f;   // exact
                a1[mt][s][j] = h;
                a2[mt][s][j] = (f16)r;
            }
        }

    // sx for this lane's 8 token slots: slot = mt*4+r -> token mt*16 + q*4 + r
    float sxr[8];
#pragma unroll
    for (int mt = 0; mt < 2; ++mt)
#pragma unroll
        for (int r = 0; r < 4; ++r)
            sxr[mt * 4 + r] = sxq[wavetok0 + mt * 16 + q * 4 + r];

    float bestd[8];
    int   besti[8];
#pragma unroll
    for (int i = 0; i < 8; ++i) { bestd[i] = 3.4e38f; besti[i] = 0x7fffffff; }

    // ---- per-lane address constants ----
    const int SLB = l5 * 131072 + lane31 * 16;     // staging source lane part
    const char* RB = wbuf + q * 512 + cl * 16;     // read base (o=s*4+q, c=cl)

    // ---- staging: 32KB per ct (2 limbs x 32 octet-slabs x 512B), 32 wave-
    // instrs, 8/wave. instr fi = wv*8+t: L = fi>>4, octet pair op = fi&15.
    auto stage = [&](int ct2, int sel) {
        const char* g1 = (const char*)W1t + ct2 * 512 + SLB;
        const char* g2 = (const char*)W2t + ct2 * 512 + SLB;
#pragma unroll
        for (int t = 0; t < 8; ++t) {
            int fi = wv * 8 + t;
            int L  = fi >> 4;             // limb (wave-uniform)
            int op = fi & 15;             // octet pair (wave-uniform)
            const char* gsrc = (L ? g2 : g1) + op * 262144;
            char* ldst = wbuf + sel * 32768 + L * 16384 + op * 1024;
            __builtin_amdgcn_global_load_lds(
                (const __attribute__((address_space(1))) unsigned int*)gsrc,
                (__attribute__((address_space(3))) unsigned int*)ldst, 16, 0, 0);
        }
    };

    const f32x4 Z = (f32x4){0.f, 0.f, 0.f, 0.f};

// one tile: stage CT+1, MFMA CT into (cm, cc) [s=0 seeds from Z], and if
// DOEPI interleave epilogue of tile CT-1 from (pm, pc) — 2 slots per s-group.
// d = fl(fl(sx+se) - 2*dot); dot*2^14 = main + 2^-11*cross.
#define VQ_TILE(CT, cm, cc, c0, c1, pm, pc, p0, p1, DOEPI)                          \
    {                                                                                \
        if ((CT) + 1 < N_CODE / 32) stage((CT) + 1, ((CT) + 1) & 1);                 \
        c0 = esq[(CT) * 32 + cl];                                                    \
        c1 = esq[(CT) * 32 + 16 + cl];                                               \
        const char* va = RB + (((CT) & 1) << 15);                                    \
        _Pragma("unroll")                                                            \
        for (int s = 0; s < 8; ++s) {                                                \
            f16x8 b1f[2], b2f[2];                                                    \
            b1f[0] = *(const f16x8*)(va + s * 2048);                                 \
            b1f[1] = *(const f16x8*)(va + s * 2048 + 256);                           \
            b2f[0] = *(const f16x8*)(va + s * 2048 + 16384);                         \
            b2f[1] = *(const f16x8*)(va + s * 2048 + 16640);                         \
            __builtin_amdgcn_s_setprio(1);                                           \
            _Pragma("unroll")                                                        \
            for (int m2 = 0; m2 < 2; ++m2)                                           \
                _Pragma("unroll")                                                    \
                for (int n2 = 0; n2 < 2; ++n2) {                                     \
                    cm[m2][n2] = __builtin_amdgcn_mfma_f32_16x16x32_f16(             \
                        a1[m2][s], b1f[n2], s ? cm[m2][n2] : Z, 0, 0, 0);            \
                    cc[m2][n2] = __builtin_amdgcn_mfma_f32_16x16x32_f16(             \
                        a2[m2][s], b1f[n2], s ? cc[m2][n2] : Z, 0, 0, 0);            \
                    cc[m2][n2] = __builtin_amdgcn_mfma_f32_16x16x32_f16(             \
                        a1[m2][s], b2f[n2], cc[m2][n2], 0, 0, 0);                    \
                }                                                                    \
            __builtin_amdgcn_s_setprio(0);                                           \
            if (DOEPI) {                                                             \
                _Pragma("unroll")                                                    \
                for (int e = 2 * s; e < 2 * s + 2; ++e) {                            \
                    const int emt = e >> 3, ent = (e >> 2) & 1, er = e & 3;          \
                    float mc = fmaf(pc[emt][ent][er], 4.8828125e-4f,                 \
                                    pm[emt][ent][er]);                               \
                    float t1 = sxr[emt * 4 + er] + (ent ? p1 : p0);                  \
                    float d  = fmaf(-1.220703125e-4f, mc, t1);                       \
                    const int slot = emt * 4 + er;                                   \
                    if (d < bestd[slot]) {                                           \
                        bestd[slot] = d;                                             \
                        besti[slot] = ((CT) - 1) * 32 + ent * 16 + cl;               \
                    }                                                                \
                }                                                                    \
            }                                                                        \
        }                                                                            \
        __syncthreads();                                                             \
    }

    stage(0, 0);
    __syncthreads();

    f32x4 Am[2][2], Ac[2][2], Bm[2][2], Bc[2][2];
    float seA0 = 0.f, seA1 = 0.f, seB0 = 0.f, seB1 = 0.f;

    VQ_TILE(0, Am, Ac, seA0, seA1, Bm, Bc, seB0, seB1, false)
    for (int k = 1; k < 254; k += 2) {
        VQ_TILE(k,     Bm, Bc, seB0, seB1, Am, Ac, seA0, seA1, true)
        VQ_TILE(k + 1, Am, Ac, seA0, seA1, Bm, Bc, seB0, seB1, true)
    }
    VQ_TILE(255, Bm, Bc, seB0, seB1, Am, Ac, seA0, seA1, true)

    // final epilogue for ct=255 (acc B); same slot/order semantics
#pragma unroll
    for (int e = 0; e < 16; ++e) {
        const int emt = e >> 3, ent = (e >> 2) & 1, er = e & 3;
        float mc = fmaf(Bc[emt][ent][er], 4.8828125e-4f, Bm[emt][ent][er]);
        float t1 = sxr[emt * 4 + er] + (ent ? seB1 : seB0);
        float d  = fmaf(-1.220703125e-4f, mc, t1);
        const int slot = emt * 4 + er;
        if (d < bestd[slot]) {
            bestd[slot] = d;
            besti[slot] = 255 * 32 + ent * 16 + cl;
        }
    }

    // ---- cross-lane reduction over the 16 code-lanes (lex (d, idx) min) ----
#pragma unroll
    for (int slot = 0; slot < 8; ++slot) {
        float d = bestd[slot];
        int   i = besti[slot];
#pragma unroll
        for (int off = 1; off < 16; off <<= 1) {
            float od = __shfl_xor(d, off, 64);
            int   oi = __shfl_xor(i, off, 64);
            if (od < d || (od == d && oi < i)) { d = od; i = oi; }
        }
        if (cl == 0)
            out_idx[wavetok0 + (slot >> 2) * 16 + q * 4 + (slot & 3)] = i;
    }
}

// ---------- kernel 4: gather + straight-through output + loss partials ----------
// atomic spread over 128 accumulators (cut same-address f64 atomic chain
// from 16384 deep to ~128; non-argmin tail 236us -> ~100us).
__global__ __launch_bounds__(256) void finalize_kernel(
    const float* __restrict__ X, const float* __restrict__ W,
    const int* __restrict__ idx, float* __restrict__ outQ,
    float* __restrict__ outI, double* __restrict__ accum) {
    __shared__ double wsum[4];
    int wid  = threadIdx.x >> 6;
    int lane = threadIdx.x & 63;
    int token = blockIdx.x * 4 + wid;
    int id = idx[token];
    float4 x = ((const float4*)(X + (size_t)token * DIM))[lane];
    float4 qv = ((const float4*)(W + (size_t)id * DIM))[lane];
    float4 o;
    o.x = x.x + (qv.x - x.x);
    o.y = x.y + (qv.y - x.y);
    o.z = x.z + (qv.z - x.z);
    o.w = x.w + (qv.w - x.w);
    ((float4*)(outQ + (size_t)token * DIM))[lane] = o;
    float dx = x.x - qv.x, dy = x.y - qv.y, dz = x.z - qv.z, dw = x.w - qv.w;
    float s = dx * dx + dy * dy + dz * dz + dw * dw;
#pragma unroll
    for (int off = 32; off; off >>= 1) s += __shfl_down(s, off, 64);
    if (lane == 0) {
        outI[token] = (float)id;
        wsum[wid] = (double)s;
    }
    __syncthreads();
    if (threadIdx.x == 0) {
        double t = wsum[0] + wsum[1] + wsum[2] + wsum[3];
        atomicAdd(&accum[blockIdx.x & 127], t);
    }
}

// ---------- kernel 5: scalars ----------
__global__ void scalars_kernel(const double* __restrict__ accum, float* __restrict__ out) {
    double mse = 0.0;
    for (int i = 0; i < 128; ++i) mse += accum[i];
    mse /= (double)((size_t)N_TOK * DIM);
    float c = (float)mse;
    out[0] = c + 0.25f * c;
    out[1] = c;
    out[2] = c;
}

extern "C" void kernel_launch(void* const* d_in, const int* in_sizes, int n_in,
                              void* d_out, int out_size, void* d_ws, size_t ws_size,
                              hipStream_t stream) {
    const float* X = (const float*)d_in[0];   // (65536, 256)
    const float* W = (const float*)d_in[1];   // (8192, 256)

    float* outQ = (float*)d_out;
    float* outI = outQ + (size_t)N_TOK * DIM;
    float* outS = outI + N_TOK;

    char* ws = (char*)d_ws;
    double* accum = (double*)ws;                         // @0, 1 KB (128 doubles)
    float* esq = (float*)(ws + 4096);                    // 32 KB
    float* sxq = (float*)(ws + 4096 + 32768);            // 256 KB
    int*   idx = (int*)(ws + 4096 + 32768 + 262144);     // 256 KB
    f16*   W1t = (f16*)(ws + (1 << 20));                 // 4 MB (k-major)
    f16*   W2t = (f16*)(ws + (1 << 20) + 4194304);       // 4 MB (k-major)

    hipMemsetAsync(accum, 0, 128 * sizeof(double), stream);
    splitw_t_kernel<<<N_CODE * 32 / 256, 256, 0, stream>>>(W, W1t, W2t);
    rowsq_kernel<<<N_CODE / 4, 256, 0, stream>>>(W, esq, N_CODE);
    rowsq_kernel<<<N_TOK / 4, 256, 0, stream>>>(X, sxq, N_TOK);
    argmin_mfma11<<<N_TOK / 128, 256, 0, stream>>>(X, W1t, W2t, sxq, esq, idx);
    finalize_kernel<<<N_TOK / 4, 256, 0, stream>>>(X, W, idx, outQ, outI, accum);
    scalars_kernel<<<1, 1, 0, stream>>>(accum, outS);
}